// Round 8
// baseline (115.451 us; speedup 1.0000x reference)
//
#include <hip/hip_runtime.h>

#define NROW 4096
#define CH   256
#define MAXNNZ 128

typedef short  short8  __attribute__((ext_vector_type(8)));
typedef unsigned short ushort8 __attribute__((ext_vector_type(8)));
typedef float  f32x4   __attribute__((ext_vector_type(4)));

__device__ inline unsigned short f2bf(float f) {
  unsigned u = __float_as_uint(f);
  return (unsigned short)((u + 0x7fffu + ((u >> 16) & 1u)) >> 16);
}
__device__ inline float bf2f(unsigned short h) {
  return __uint_as_float((unsigned)h << 16);
}
__device__ inline int mbcnt64(unsigned long long m, int base) {
  int t = __builtin_amdgcn_mbcnt_lo((unsigned)m, (unsigned)base);
  return __builtin_amdgcn_mbcnt_hi((unsigned)(m >> 32), t);
}

// ---------------------------------------------------------------------------
// Build 3 CSRs (Ld, Lup, P). One WAVE per row. The 16 row-loads are forced
// into flight TOGETHER via one inline-asm block (early-clobber dests => 64
// disjoint data VGPRs; single s_waitcnt vmcnt(0) inside the block). This is
// the fix for 3 rounds of the compiler serializing the loads (VGPR=36).
__global__ __launch_bounds__(256, 4) void build_csr3(
    const float* __restrict__ L0, const float* __restrict__ L1,
    const float* __restrict__ L2, int* __restrict__ idx,
    float* __restrict__ val, int* __restrict__ cnt) {
  __shared__ int   sj[4][MAXNNZ];
  __shared__ float sv[4][MAXNNZ];
  const int mat = blockIdx.y;
  const float* L = (mat == 0) ? L0 : (mat == 1) ? L1 : L2;
  const int wi = threadIdx.x >> 6, lane = threadIdx.x & 63;
  const int row = blockIdx.x * 4 + wi;

  const char* pb = (const char*)(L + (size_t)row * NROW) + lane * 16;
  const char* p1 = pb + 4096;
  const char* p2 = pb + 8192;
  const char* p3 = pb + 12288;

  f32x4 v0, v1, v2, v3, v4, v5, v6, v7, v8, v9, v10, v11, v12, v13, v14, v15;
  asm volatile(
      "global_load_dwordx4 %[d0],  %[a0], off\n\t"
      "global_load_dwordx4 %[d1],  %[a0], off offset:1024\n\t"
      "global_load_dwordx4 %[d2],  %[a0], off offset:2048\n\t"
      "global_load_dwordx4 %[d3],  %[a0], off offset:3072\n\t"
      "global_load_dwordx4 %[d4],  %[a1], off\n\t"
      "global_load_dwordx4 %[d5],  %[a1], off offset:1024\n\t"
      "global_load_dwordx4 %[d6],  %[a1], off offset:2048\n\t"
      "global_load_dwordx4 %[d7],  %[a1], off offset:3072\n\t"
      "global_load_dwordx4 %[d8],  %[a2], off\n\t"
      "global_load_dwordx4 %[d9],  %[a2], off offset:1024\n\t"
      "global_load_dwordx4 %[d10], %[a2], off offset:2048\n\t"
      "global_load_dwordx4 %[d11], %[a2], off offset:3072\n\t"
      "global_load_dwordx4 %[d12], %[a3], off\n\t"
      "global_load_dwordx4 %[d13], %[a3], off offset:1024\n\t"
      "global_load_dwordx4 %[d14], %[a3], off offset:2048\n\t"
      "global_load_dwordx4 %[d15], %[a3], off offset:3072\n\t"
      "s_waitcnt vmcnt(0)"
      : [d0] "=&v"(v0),  [d1] "=&v"(v1),  [d2] "=&v"(v2),  [d3] "=&v"(v3),
        [d4] "=&v"(v4),  [d5] "=&v"(v5),  [d6] "=&v"(v6),  [d7] "=&v"(v7),
        [d8] "=&v"(v8),  [d9] "=&v"(v9),  [d10] "=&v"(v10), [d11] "=&v"(v11),
        [d12] "=&v"(v12), [d13] "=&v"(v13), [d14] "=&v"(v14), [d15] "=&v"(v15)
      : [a0] "v"(pb), [a1] "v"(p1), [a2] "v"(p2), [a3] "v"(p3)
      : "memory");

  int base = 0;
#define PROCQ(q, cb) {                                                         \
    bool a0 = q[0] != 0.f, a1 = q[1] != 0.f, a2 = q[2] != 0.f, a3 = q[3] != 0.f; \
    unsigned long long b0 = __ballot(a0), b1 = __ballot(a1);                   \
    unsigned long long b2 = __ballot(a2), b3 = __ballot(a3);                   \
    int off = mbcnt64(b3, mbcnt64(b2, mbcnt64(b1, mbcnt64(b0, base))));        \
    if (a0) { if (off < MAXNNZ) { sj[wi][off] = (cb);     sv[wi][off] = q[0]; } ++off; } \
    if (a1) { if (off < MAXNNZ) { sj[wi][off] = (cb) + 1; sv[wi][off] = q[1]; } ++off; } \
    if (a2) { if (off < MAXNNZ) { sj[wi][off] = (cb) + 2; sv[wi][off] = q[2]; } ++off; } \
    if (a3) { if (off < MAXNNZ) { sj[wi][off] = (cb) + 3; sv[wi][off] = q[3]; } ++off; } \
    base += __popcll(b0) + __popcll(b1) + __popcll(b2) + __popcll(b3); }
  int cb = lane * 4;
  PROCQ(v0,  cb)        PROCQ(v1,  cb + 256)  PROCQ(v2,  cb + 512)  PROCQ(v3,  cb + 768)
  PROCQ(v4,  cb + 1024) PROCQ(v5,  cb + 1280) PROCQ(v6,  cb + 1536) PROCQ(v7,  cb + 1792)
  PROCQ(v8,  cb + 2048) PROCQ(v9,  cb + 2304) PROCQ(v10, cb + 2560) PROCQ(v11, cb + 2816)
  PROCQ(v12, cb + 3072) PROCQ(v13, cb + 3328) PROCQ(v14, cb + 3584) PROCQ(v15, cb + 3840)
#undef PROCQ

  size_t rbase = ((size_t)mat * NROW + row) * MAXNNZ;
  int2   ji = ((const int2*)sj[wi])[lane];
  float2 vf = ((const float2*)sv[wi])[lane];
  ((int2*)(idx + rbase))[lane] = ji;
  ((float2*)(val + rbase))[lane] = vf;
  if (lane == 0) cnt[mat * NROW + row] = base < MAXNNZ ? base : MAXNNZ;
}

// ---------------------------------------------------------------------------
// One dispatch converting x, Wirr_w, Wsol_w, Whar_w to bf16 (4 f32/thread).
__global__ void cvt_all(const float* __restrict__ x, const float* __restrict__ Wi,
                        const float* __restrict__ Ws, const float* __restrict__ Wh,
                        unsigned short* __restrict__ xbf, unsigned short* __restrict__ Bbf) {
  int i = blockIdx.x * 256 + threadIdx.x;       // float4 index
  const float* src; unsigned short* dst; int o;
  if (i < 262144)        { src = x;  dst = xbf;          o = i; }
  else if (i < 294912)   { src = Wi; dst = Bbf;          o = i - 262144; }
  else if (i < 327680)   { src = Ws; dst = Bbf + 131072; o = i - 294912; }
  else                   { src = Wh; dst = Bbf + 262144; o = i - 327680; }
  float4 v = ((const float4*)src)[o];
  ushort4 u;
  u.x = f2bf(v.x); u.y = f2bf(v.y); u.z = f2bf(v.z); u.w = f2bf(v.w);
  ((ushort4*)dst)[o] = u;
}

// ---------------------------------------------------------------------------
// Y[4096][1280] (bf16) = A[4096][256](bf16) @ Bt[1280][256](bf16)^T
__global__ __launch_bounds__(256, 2) void gemm_mfma(const unsigned short* __restrict__ A,
                                                    const unsigned short* __restrict__ Bt,
                                                    unsigned short* __restrict__ Y) {
  __shared__ unsigned short sA[64 * 256];
  __shared__ unsigned short sB[64 * 256];
  const int m0 = blockIdx.x * 64, n0 = blockIdx.y * 64;
  const int tid = threadIdx.x, wid = tid >> 6, lane = tid & 63;

  for (int c = 0; c < 8; ++c) {
    int chunk = c * 256 + tid;
    int r  = chunk >> 5;
    int cb = (chunk & 31) * 16;
    int cbs = cb ^ ((r & 7) << 4);
    ushort8 va = *(const ushort8*)((const char*)(A  + (size_t)(m0 + r) * 256) + cb);
    *(ushort8*)((char*)sA + r * 512 + cbs) = va;
    ushort8 vb = *(const ushort8*)((const char*)(Bt + (size_t)(n0 + r) * 256) + cb);
    *(ushort8*)((char*)sB + r * 512 + cbs) = vb;
  }
  __syncthreads();

  const int wr = wid >> 1, wc = wid & 1;
  const int lr = lane & 15, kg = lane >> 4;
  f32x4 acc[2][2] = {};
#pragma unroll
  for (int ks = 0; ks < 8; ++ks) {
    int kb = ks * 64 + kg * 16;
    short8 a0, a1, b0, b1;
    { int r = wr * 32 + lr;      a0 = *(const short8*)((const char*)sA + r * 512 + (kb ^ ((r & 7) << 4))); }
    { int r = wr * 32 + 16 + lr; a1 = *(const short8*)((const char*)sA + r * 512 + (kb ^ ((r & 7) << 4))); }
    { int r = wc * 32 + lr;      b0 = *(const short8*)((const char*)sB + r * 512 + (kb ^ ((r & 7) << 4))); }
    { int r = wc * 32 + 16 + lr; b1 = *(const short8*)((const char*)sB + r * 512 + (kb ^ ((r & 7) << 4))); }
    acc[0][0] = __builtin_amdgcn_mfma_f32_16x16x32_bf16(a0, b0, acc[0][0], 0, 0, 0);
    acc[0][1] = __builtin_amdgcn_mfma_f32_16x16x32_bf16(a0, b1, acc[0][1], 0, 0, 0);
    acc[1][0] = __builtin_amdgcn_mfma_f32_16x16x32_bf16(a1, b0, acc[1][0], 0, 0, 0);
    acc[1][1] = __builtin_amdgcn_mfma_f32_16x16x32_bf16(a1, b1, acc[1][1], 0, 0, 0);
  }

#pragma unroll
  for (int mi = 0; mi < 2; ++mi)
#pragma unroll
    for (int ni = 0; ni < 2; ++ni) {
      int col = n0 + wc * 32 + ni * 16 + lr;
#pragma unroll
      for (int r4 = 0; r4 < 4; ++r4) {
        int row = m0 + wr * 32 + mi * 16 + kg * 4 + r4;
        Y[(size_t)row * 1280 + col] = f2bf(acc[mi][ni][r4]);
      }
    }
}

// ---------------------------------------------------------------------------
// sdv[q][row] from Y: cols 0-511 are x_cat_irr, 512-1023 x_cat_sol.
__global__ __launch_bounds__(256) void sdv_from_y(
    const unsigned short* __restrict__ Y, const float* __restrict__ ai,
    const float* __restrict__ as_, const float* __restrict__ bi,
    const float* __restrict__ bs, float* __restrict__ sdv) {
  __shared__ float satt[2048];
  __shared__ float sbias[4];
  int t = threadIdx.x, wi = t >> 6, lane = t & 63;
  for (int k = t; k < 1024; k += 256) { satt[k] = ai[k]; satt[1024 + k] = as_[k]; }
  {
    const float* av = (wi & 2) ? as_ : ai;
    const float* bv = (wi & 2) ? bs : bi;
    int off = (wi & 1) * 512;
    float b = 0.f;
    for (int k = lane; k < 512; k += 64) b += av[off + k] * bv[k];
    for (int o = 32; o; o >>= 1) b += __shfl_xor(b, o);
    if (lane == 0) sbias[wi] = b;
  }
  __syncthreads();

  int row = blockIdx.x * 4 + wi;
  const ushort8* yr = (const ushort8*)(Y + (size_t)row * 1280);
  ushort8 ya = yr[lane * 2], yb = yr[lane * 2 + 1];
  int c0 = lane * 16;
  int off = (lane < 32) ? 0 : 512;
  float a0 = 0.f, a1 = 0.f;
#pragma unroll
  for (int j = 0; j < 8; ++j) {
    float y = bf2f(ya[j]); int c = c0 + j;
    a0 += satt[off + c] * y; a1 += satt[off + 512 + c] * y;
  }
#pragma unroll
  for (int j = 0; j < 8; ++j) {
    float y = bf2f(yb[j]); int c = c0 + 8 + j;
    a0 += satt[off + c] * y; a1 += satt[off + 512 + c] * y;
  }
  for (int o = 16; o; o >>= 1) { a0 += __shfl_xor(a0, o); a1 += __shfl_xor(a1, o); }
  if (lane == 0)  { sdv[row] = a0 + sbias[0];            sdv[NROW + row] = a1 + sbias[1]; }
  if (lane == 32) { sdv[2 * NROW + row] = a0 + sbias[2]; sdv[3 * NROW + row] = a1 + sbias[3]; }
}

// ---------------------------------------------------------------------------
// U = Y0 + L @ Y1 (in place into the Y0 column range). 4-wave k-split,
// ushort4 (8B/lane) gathers, cross-wave LDS reduce.
__global__ __launch_bounds__(256) void spmm_add(const int* __restrict__ idx,
                                                const float* __restrict__ val,
                                                const int* __restrict__ cnt,
                                                unsigned short* __restrict__ Y) {
  int br = blockIdx.y, row = blockIdx.x;
  int t = threadIdx.x, w = t >> 6, l = t & 63;
  __shared__ int   sj[MAXNNZ];
  __shared__ float sv[MAXNNZ];
  __shared__ float part[4][256];
  size_t rbase = ((size_t)br * NROW + row) * MAXNNZ;
  int n = cnt[br * NROW + row];
  if (t < n) { sj[t] = idx[rbase + t]; sv[t] = val[rbase + t]; }
  __syncthreads();
  int cs = br ? 768 : 256, cd = br ? 512 : 0;
  float4 acc = {0.f, 0.f, 0.f, 0.f};
  for (int k = w; k < n; k += 4) {
    ushort4 y = *(const ushort4*)(Y + (size_t)sj[k] * 1280 + cs + 4 * l);
    float a = sv[k];
    acc.x += a * bf2f(y.x); acc.y += a * bf2f(y.y);
    acc.z += a * bf2f(y.z); acc.w += a * bf2f(y.w);
  }
  ((float4*)part[w])[l] = acc;
  __syncthreads();
  if (t < 64) {
    unsigned short* yp = Y + (size_t)row * 1280 + cd + 4 * t;
    ushort4 yb = *(const ushort4*)yp;
    ushort4 o;
    o.x = f2bf(bf2f(yb.x) + part[0][4 * t]     + part[1][4 * t]     + part[2][4 * t]     + part[3][4 * t]);
    o.y = f2bf(bf2f(yb.y) + part[0][4 * t + 1] + part[1][4 * t + 1] + part[2][4 * t + 1] + part[3][4 * t + 1]);
    o.z = f2bf(bf2f(yb.z) + part[0][4 * t + 2] + part[1][4 * t + 2] + part[2][4 * t + 2] + part[3][4 * t + 2]);
    o.w = f2bf(bf2f(yb.w) + part[0][4 * t + 3] + part[1][4 * t + 3] + part[2][4 * t + 3] + part[3][4 * t + 3]);
    *(ushort4*)yp = o;
  }
}

// ---------------------------------------------------------------------------
// Z[row] = alpha_d @ U_d + alpha_s @ U_s + P @ Yh + (all biases)
__global__ __launch_bounds__(256) void final_z(const int* __restrict__ idx,
                        const float* __restrict__ val, const int* __restrict__ cnt,
                        const float* __restrict__ sdv,
                        const unsigned short* __restrict__ Y,
                        const float* __restrict__ bi, const float* __restrict__ bs,
                        const float* __restrict__ bh, float* __restrict__ Z) {
  int row = blockIdx.x, t = threadIdx.x, w = t >> 6, l = t & 63;
  __shared__ float sa[MAXNNZ];
  __shared__ int   sj[MAXNNZ];
  __shared__ float red[4];
  __shared__ float part[4][256];
  float4 acc = {0.f, 0.f, 0.f, 0.f};

  for (int br = 0; br < 2; ++br) {
    size_t rbase = ((size_t)br * NROW + row) * MAXNNZ;
    int n = cnt[br * NROW + row];
    const float* srcv = sdv + (2 * br) * NROW;
    const float* dstv = sdv + (2 * br + 1) * NROW;
    float e = -1e30f;
    if (t < n) {
      int j = idx[rbase + t];
      sj[t] = j;
      float v = srcv[row] + dstv[j];
      e = v >= 0.f ? v : 0.01f * v;
    }
    float m = e;
    for (int o = 32; o; o >>= 1) m = fmaxf(m, __shfl_xor(m, o));
    if ((t & 63) == 0) red[t >> 6] = m;
    __syncthreads();
    m = fmaxf(fmaxf(red[0], red[1]), fmaxf(red[2], red[3]));
    __syncthreads();
    float p = (t < n) ? expf(e - m) : 0.f;
    float s = p;
    for (int o = 32; o; o >>= 1) s += __shfl_xor(s, o);
    if ((t & 63) == 0) red[t >> 6] = s;
    __syncthreads();
    s = red[0] + red[1] + red[2] + red[3];
    if (t < n) sa[t] = p / s;
    __syncthreads();
    int cd = br ? 512 : 0;
    for (int k = w; k < n; k += 4) {
      ushort4 y = *(const ushort4*)(Y + (size_t)sj[k] * 1280 + cd + 4 * l);
      float a = sa[k];
      acc.x += a * bf2f(y.x); acc.y += a * bf2f(y.y);
      acc.z += a * bf2f(y.z); acc.w += a * bf2f(y.w);
    }
    __syncthreads();   // before next branch rewrites sa/sj/red
  }

  {
    size_t rbase = ((size_t)2 * NROW + row) * MAXNNZ;
    int n = cnt[2 * NROW + row];
    if (t < n) { sj[t] = idx[rbase + t]; sa[t] = val[rbase + t]; }
    __syncthreads();
    for (int k = w; k < n; k += 4) {
      ushort4 y = *(const ushort4*)(Y + (size_t)sj[k] * 1280 + 1024 + 4 * l);
      float a = sa[k];
      acc.x += a * bf2f(y.x); acc.y += a * bf2f(y.y);
      acc.z += a * bf2f(y.z); acc.w += a * bf2f(y.w);
    }
  }
  ((float4*)part[w])[l] = acc;
  __syncthreads();
  if (t < 64) {
    float4 r;
    int c = 4 * t;
    r.x = part[0][c]     + part[1][c]     + part[2][c]     + part[3][c]     + bi[c]     + bi[256 + c]     + bs[c]     + bs[256 + c]     + bh[c];
    r.y = part[0][c + 1] + part[1][c + 1] + part[2][c + 1] + part[3][c + 1] + bi[c + 1] + bi[257 + c]     + bs[c + 1] + bs[257 + c]     + bh[c + 1];
    r.z = part[0][c + 2] + part[1][c + 2] + part[2][c + 2] + part[3][c + 2] + bi[c + 2] + bi[258 + c]     + bs[c + 2] + bs[258 + c]     + bh[c + 2];
    r.w = part[0][c + 3] + part[1][c + 3] + part[2][c + 3] + part[3][c + 3] + bi[c + 3] + bi[259 + c]     + bs[c + 3] + bs[259 + c]     + bh[c + 3];
    *(float4*)(Z + (size_t)row * 256 + c) = r;
  }
}

// ---------------------------------------------------------------------------
extern "C" void kernel_launch(void* const* d_in, const int* in_sizes, int n_in,
                              void* d_out, int out_size, void* d_ws, size_t ws_size,
                              hipStream_t stream) {
  const float* x      = (const float*)d_in[0];
  const float* Lup    = (const float*)d_in[1];
  const float* Ld     = (const float*)d_in[2];
  const float* P      = (const float*)d_in[3];
  const float* Wirr_w = (const float*)d_in[4];
  const float* Wirr_b = (const float*)d_in[5];
  const float* Wsol_w = (const float*)d_in[6];
  const float* Wsol_b = (const float*)d_in[7];
  const float* Whar_w = (const float*)d_in[8];
  const float* Whar_b = (const float*)d_in[9];
  const float* att_i  = (const float*)d_in[10];
  const float* att_s  = (const float*)d_in[11];
  float* Z = (float*)d_out;

  char* w = (char*)d_ws;
  auto alloc = [&](size_t bytes) { void* p = (void*)w; w += (bytes + 255) & ~(size_t)255; return p; };

  int*   idx  = (int*)alloc((size_t)3 * NROW * MAXNNZ * 4);
  float* val  = (float*)alloc((size_t)3 * NROW * MAXNNZ * 4);
  int*   cnt  = (int*)alloc((size_t)3 * NROW * 4);
  float* sdv  = (float*)alloc(4 * NROW * 4);
  unsigned short* xbf = (unsigned short*)alloc((size_t)NROW * CH * 2);
  unsigned short* Bbf = (unsigned short*)alloc((size_t)1280 * CH * 2);
  unsigned short* Y   = (unsigned short*)alloc((size_t)NROW * 1280 * 2);

  // mat slot order: 0 = Ld (irr), 1 = Lup (sol), 2 = P
  build_csr3<<<dim3(NROW / 4, 3), 256, 0, stream>>>(Ld, Lup, P, idx, val, cnt);

  cvt_all<<<(262144 + 32768 + 32768 + 16384) / 256, 256, 0, stream>>>(x, Wirr_w, Wsol_w, Whar_w, xbf, Bbf);

  gemm_mfma<<<dim3(NROW / 64, 1280 / 64), 256, 0, stream>>>(xbf, Bbf, Y);

  sdv_from_y<<<NROW / 4, 256, 0, stream>>>(Y, att_i, att_s, Wirr_b, Wsol_b, sdv);

  spmm_add<<<dim3(NROW, 2), 256, 0, stream>>>(idx, val, cnt, Y);

  final_z<<<NROW, 256, 0, stream>>>(idx, val, cnt, sdv, Y, Wirr_b, Wsol_b, Whar_b, Z);
}

// Round 9
// 107.782 us; speedup vs baseline: 1.0712x; 1.0712x over previous
//
#include <hip/hip_runtime.h>

#define NROW 4096
#define CH   256
#define MAXNNZ 128

typedef short  short8  __attribute__((ext_vector_type(8)));
typedef unsigned short ushort8 __attribute__((ext_vector_type(8)));
typedef float  f32x4   __attribute__((ext_vector_type(4)));

__device__ inline unsigned short f2bf(float f) {
  unsigned u = __float_as_uint(f);
  return (unsigned short)((u + 0x7fffu + ((u >> 16) & 1u)) >> 16);
}
__device__ inline float bf2f(unsigned short h) {
  return __uint_as_float((unsigned)h << 16);
}
__device__ inline int mbcnt64(unsigned long long m, int base) {
  int t = __builtin_amdgcn_mbcnt_lo((unsigned)m, (unsigned)base);
  return __builtin_amdgcn_mbcnt_hi((unsigned)(m >> 32), t);
}

// ---------------------------------------------------------------------------
// One dispatch converting x, Wirr_w, Wsol_w, Whar_w to bf16 (4 f32/thread).
__global__ void cvt_all(const float* __restrict__ x, const float* __restrict__ Wi,
                        const float* __restrict__ Ws, const float* __restrict__ Wh,
                        unsigned short* __restrict__ xbf, unsigned short* __restrict__ Bbf) {
  int i = blockIdx.x * 256 + threadIdx.x;       // float4 index
  const float* src; unsigned short* dst; int o;
  if (i < 262144)        { src = x;  dst = xbf;          o = i; }
  else if (i < 294912)   { src = Wi; dst = Bbf;          o = i - 262144; }
  else if (i < 327680)   { src = Ws; dst = Bbf + 131072; o = i - 294912; }
  else                   { src = Wh; dst = Bbf + 262144; o = i - 327680; }
  float4 v = ((const float4*)src)[o];
  ushort4 u;
  u.x = f2bf(v.x); u.y = f2bf(v.y); u.z = f2bf(v.z); u.w = f2bf(v.w);
  ((ushort4*)dst)[o] = u;
}

// ---------------------------------------------------------------------------
// FUSED: 12288 CSR-scan blocks (round-5 structure: one block per (mat,row),
// 4 waves x 1024-col segment, ballot-compaction, block stitch) + 1280 MFMA
// GEMM tile blocks (64x64, BK=128 double-stage, 32KB LDS) interleaved every
// 10th block. The scan is a ~2.6TB/s throughput-wall (6 structures tried,
// latency-insensitive); the compute-bound GEMM hides inside its stalls.
__global__ __launch_bounds__(256) void scan_gemm(
    const float* __restrict__ L0, const float* __restrict__ L1,
    const float* __restrict__ L2, int* __restrict__ idx,
    float* __restrict__ val, int* __restrict__ cnt,
    const unsigned short* __restrict__ A, const unsigned short* __restrict__ Bt,
    unsigned short* __restrict__ Y) {
  __shared__ __align__(16) union {
    struct { unsigned short sA[64 * 128]; unsigned short sB[64 * 128]; } g;   // 32 KB
    struct { int sj[4][MAXNNZ]; float sv[4][MAXNNZ]; int scnt[4]; } c;        // 4.1 KB
  } u;
  const int bid = blockIdx.x, tid = threadIdx.x;
  const bool is_gemm = (bid < 12800) && (bid % 10 == 9);

  if (is_gemm) {
    const int gid = bid / 10;
    const int m0 = (gid & 63) * 64, n0 = (gid >> 6) * 64;
    const int wid = tid >> 6, lane = tid & 63;
    const int wr = wid >> 1, wc = wid & 1, lr = lane & 15, kg = lane >> 4;
    f32x4 acc[2][2] = {};
#pragma unroll
    for (int kh = 0; kh < 2; ++kh) {
      for (int c = 0; c < 4; ++c) {
        int chunk = c * 256 + tid;          // 0..1023
        int r  = chunk >> 4;                // 16 chunks per 256B row
        int cb = (chunk & 15) * 16;
        int cbs = cb ^ ((r & 7) << 4);
        ushort8 va = *(const ushort8*)((const char*)A  + (size_t)(m0 + r) * 512 + kh * 256 + cb);
        *(ushort8*)((char*)u.g.sA + r * 256 + cbs) = va;
        ushort8 vb = *(const ushort8*)((const char*)Bt + (size_t)(n0 + r) * 512 + kh * 256 + cb);
        *(ushort8*)((char*)u.g.sB + r * 256 + cbs) = vb;
      }
      __syncthreads();
#pragma unroll
      for (int ks = 0; ks < 4; ++ks) {
        int kb = ks * 64 + kg * 16;
        short8 a0, a1, b0, b1;
        { int r = wr * 32 + lr;      a0 = *(const short8*)((const char*)u.g.sA + r * 256 + (kb ^ ((r & 7) << 4))); }
        { int r = wr * 32 + 16 + lr; a1 = *(const short8*)((const char*)u.g.sA + r * 256 + (kb ^ ((r & 7) << 4))); }
        { int r = wc * 32 + lr;      b0 = *(const short8*)((const char*)u.g.sB + r * 256 + (kb ^ ((r & 7) << 4))); }
        { int r = wc * 32 + 16 + lr; b1 = *(const short8*)((const char*)u.g.sB + r * 256 + (kb ^ ((r & 7) << 4))); }
        acc[0][0] = __builtin_amdgcn_mfma_f32_16x16x32_bf16(a0, b0, acc[0][0], 0, 0, 0);
        acc[0][1] = __builtin_amdgcn_mfma_f32_16x16x32_bf16(a0, b1, acc[0][1], 0, 0, 0);
        acc[1][0] = __builtin_amdgcn_mfma_f32_16x16x32_bf16(a1, b0, acc[1][0], 0, 0, 0);
        acc[1][1] = __builtin_amdgcn_mfma_f32_16x16x32_bf16(a1, b1, acc[1][1], 0, 0, 0);
      }
      __syncthreads();
    }
#pragma unroll
    for (int mi = 0; mi < 2; ++mi)
#pragma unroll
      for (int ni = 0; ni < 2; ++ni) {
        int col = n0 + wc * 32 + ni * 16 + lr;
#pragma unroll
        for (int r4 = 0; r4 < 4; ++r4) {
          int row = m0 + wr * 32 + mi * 16 + kg * 4 + r4;
          Y[(size_t)row * 1280 + col] = f2bf(acc[mi][ni][r4]);
        }
      }
  } else {
    const int cid = bid - ((bid < 12800) ? (bid + 1) / 10 : 1280);
    const int mat = cid >> 12, row = cid & 4095;
    const float* L = (mat == 0) ? L0 : (mat == 1) ? L1 : L2;
    const int wi = tid >> 6, lane = tid & 63;
    const float4* Lseg = (const float4*)(L + (size_t)row * NROW) + wi * 256;

    float4 v0 = Lseg[lane], v1 = Lseg[64 + lane], v2 = Lseg[128 + lane], v3 = Lseg[192 + lane];

    int base = 0;
    float4 vv[4] = {v0, v1, v2, v3};
#pragma unroll
    for (int k = 0; k < 4; ++k) {
      float4 q = vv[k];
      bool n0_ = q.x != 0.f, n1_ = q.y != 0.f, n2_ = q.z != 0.f, n3_ = q.w != 0.f;
      unsigned long long b0 = __ballot(n0_), b1 = __ballot(n1_);
      unsigned long long b2 = __ballot(n2_), b3 = __ballot(n3_);
      int off = mbcnt64(b3, mbcnt64(b2, mbcnt64(b1, mbcnt64(b0, base))));
      int col0 = wi * 1024 + k * 256 + lane * 4;
      if (n0_) { if (off < MAXNNZ) { u.c.sj[wi][off] = col0;     u.c.sv[wi][off] = q.x; } ++off; }
      if (n1_) { if (off < MAXNNZ) { u.c.sj[wi][off] = col0 + 1; u.c.sv[wi][off] = q.y; } ++off; }
      if (n2_) { if (off < MAXNNZ) { u.c.sj[wi][off] = col0 + 2; u.c.sv[wi][off] = q.z; } ++off; }
      if (n3_) { if (off < MAXNNZ) { u.c.sj[wi][off] = col0 + 3; u.c.sv[wi][off] = q.w; } ++off; }
      base += __popcll(b0) + __popcll(b1) + __popcll(b2) + __popcll(b3);
    }
    if (lane == 0) u.c.scnt[wi] = base < MAXNNZ ? base : MAXNNZ;
    __syncthreads();

    int c0 = u.c.scnt[0], c1 = u.c.scnt[1], c2 = u.c.scnt[2], c3 = u.c.scnt[3];
    int total = c0 + c1 + c2 + c3;
    if (total > MAXNNZ) total = MAXNNZ;
    size_t rbase = ((size_t)mat * NROW + row) * MAXNNZ;
    int t = tid;
    if (t < total) {
      int s, o;
      if      (t < c0)           { s = 0; o = t; }
      else if (t < c0 + c1)      { s = 1; o = t - c0; }
      else if (t < c0 + c1 + c2) { s = 2; o = t - c0 - c1; }
      else                       { s = 3; o = t - c0 - c1 - c2; }
      idx[rbase + t] = u.c.sj[s][o];
      val[rbase + t] = u.c.sv[s][o];
    }
    if (t == 0) cnt[mat * NROW + row] = total;
  }
}

// ---------------------------------------------------------------------------
// MERGED per-row kernel: sdv (att-dots on own row's Y[0..1023]) + BOTH
// spmm_add branches (U_d -> cols 0-255, U_s -> cols 512-767). Gathers read
// only cols 256-511 / 768-1023 (never written) -> no cross-block race.
__global__ __launch_bounds__(256) void spmm_sdv(
    const int* __restrict__ idx, const float* __restrict__ val,
    const int* __restrict__ cnt, const float* __restrict__ ai,
    const float* __restrict__ as_, const float* __restrict__ bi,
    const float* __restrict__ bs, unsigned short* __restrict__ Y,
    float* __restrict__ sdv) {
  int row = blockIdx.x, t = threadIdx.x, w = t >> 6, l = t & 63;
  __shared__ float satt[2048];
  __shared__ float red2[8];
  __shared__ float sbias[4];
  __shared__ int   sj0[MAXNNZ], sj1[MAXNNZ];
  __shared__ float sv0[MAXNNZ], sv1[MAXNNZ];
  __shared__ float part[4][256];

  for (int k = t; k < 1024; k += 256) { satt[k] = ai[k]; satt[1024 + k] = as_[k]; }
  {
    const float* av = (w & 2) ? as_ : ai;
    const float* bv = (w & 2) ? bs : bi;
    int off = (w & 1) * 512;
    float b = 0.f;
    for (int k = l; k < 512; k += 64) b += av[off + k] * bv[k];
    for (int o = 32; o; o >>= 1) b += __shfl_xor(b, o);
    if (l == 0) sbias[w] = b;
  }
  int n0 = cnt[row], n1 = cnt[NROW + row];
  if (t < n0) { sj0[t] = idx[(size_t)row * MAXNNZ + t];          sv0[t] = val[(size_t)row * MAXNNZ + t]; }
  if (t < n1) { sj1[t] = idx[((size_t)NROW + row) * MAXNNZ + t]; sv1[t] = val[((size_t)NROW + row) * MAXNNZ + t]; }
  ushort4 y4 = *(const ushort4*)(Y + (size_t)row * 1280 + 4 * t);   // own row, pre-overwrite
  __syncthreads();

  // sdv partials: threads 0-127 = irr (cols 0-1023 lower half), 128-255 = sol
  {
    int c0 = 4 * t;
    int aoff = (t < 128) ? 0 : 1024;
    int cc = c0 & 511;
    float sp = satt[aoff + cc]       * bf2f(y4.x) + satt[aoff + cc + 1]       * bf2f(y4.y)
             + satt[aoff + cc + 2]   * bf2f(y4.z) + satt[aoff + cc + 3]       * bf2f(y4.w);
    float dp = satt[aoff + 512 + cc] * bf2f(y4.x) + satt[aoff + 512 + cc + 1] * bf2f(y4.y)
             + satt[aoff + 512 + cc + 2] * bf2f(y4.z) + satt[aoff + 512 + cc + 3] * bf2f(y4.w);
    for (int o = 32; o; o >>= 1) { sp += __shfl_xor(sp, o); dp += __shfl_xor(dp, o); }
    if (l == 0) { red2[w * 2] = sp; red2[w * 2 + 1] = dp; }
  }

  // both-branch gathers (k-split across 4 waves, 8B/lane)
  float4 acc0 = {0.f, 0.f, 0.f, 0.f}, acc1 = {0.f, 0.f, 0.f, 0.f};
  for (int k = w; k < n0; k += 4) {
    ushort4 y = *(const ushort4*)(Y + (size_t)sj0[k] * 1280 + 256 + 4 * l);
    float a = sv0[k];
    acc0.x += a * bf2f(y.x); acc0.y += a * bf2f(y.y);
    acc0.z += a * bf2f(y.z); acc0.w += a * bf2f(y.w);
  }
  for (int k = w; k < n1; k += 4) {
    ushort4 y = *(const ushort4*)(Y + (size_t)sj1[k] * 1280 + 768 + 4 * l);
    float a = sv1[k];
    acc1.x += a * bf2f(y.x); acc1.y += a * bf2f(y.y);
    acc1.z += a * bf2f(y.z); acc1.w += a * bf2f(y.w);
  }
  ((float4*)part[w])[l] = acc0;
  __syncthreads();
  if (t == 0) {
    sdv[row]            = red2[0] + red2[2] + sbias[0];
    sdv[NROW + row]     = red2[1] + red2[3] + sbias[1];
    sdv[2 * NROW + row] = red2[4] + red2[6] + sbias[2];
    sdv[3 * NROW + row] = red2[5] + red2[7] + sbias[3];
  }
  if (t < 64) {
    unsigned short* yp = Y + (size_t)row * 1280 + 4 * t;
    ushort4 yb = *(const ushort4*)yp;
    ushort4 o;
    o.x = f2bf(bf2f(yb.x) + part[0][4 * t]     + part[1][4 * t]     + part[2][4 * t]     + part[3][4 * t]);
    o.y = f2bf(bf2f(yb.y) + part[0][4 * t + 1] + part[1][4 * t + 1] + part[2][4 * t + 1] + part[3][4 * t + 1]);
    o.z = f2bf(bf2f(yb.z) + part[0][4 * t + 2] + part[1][4 * t + 2] + part[2][4 * t + 2] + part[3][4 * t + 2]);
    o.w = f2bf(bf2f(yb.w) + part[0][4 * t + 3] + part[1][4 * t + 3] + part[2][4 * t + 3] + part[3][4 * t + 3]);
    *(ushort4*)yp = o;
  }
  __syncthreads();
  ((float4*)part[w])[l] = acc1;
  __syncthreads();
  if (t < 64) {
    unsigned short* yp = Y + (size_t)row * 1280 + 512 + 4 * t;
    ushort4 yb = *(const ushort4*)yp;
    ushort4 o;
    o.x = f2bf(bf2f(yb.x) + part[0][4 * t]     + part[1][4 * t]     + part[2][4 * t]     + part[3][4 * t]);
    o.y = f2bf(bf2f(yb.y) + part[0][4 * t + 1] + part[1][4 * t + 1] + part[2][4 * t + 1] + part[3][4 * t + 1]);
    o.z = f2bf(bf2f(yb.z) + part[0][4 * t + 2] + part[1][4 * t + 2] + part[2][4 * t + 2] + part[3][4 * t + 2]);
    o.w = f2bf(bf2f(yb.w) + part[0][4 * t + 3] + part[1][4 * t + 3] + part[2][4 * t + 3] + part[3][4 * t + 3]);
    *(ushort4*)yp = o;
  }
}

// ---------------------------------------------------------------------------
// Z[row] = alpha_d @ U_d + alpha_s @ U_s + P @ Yh + (all biases)
__global__ __launch_bounds__(256) void final_z(const int* __restrict__ idx,
                        const float* __restrict__ val, const int* __restrict__ cnt,
                        const float* __restrict__ sdv,
                        const unsigned short* __restrict__ Y,
                        const float* __restrict__ bi, const float* __restrict__ bs,
                        const float* __restrict__ bh, float* __restrict__ Z) {
  int row = blockIdx.x, t = threadIdx.x, w = t >> 6, l = t & 63;
  __shared__ float sa[MAXNNZ];
  __shared__ int   sj[MAXNNZ];
  __shared__ float red[4];
  __shared__ float part[4][256];
  float4 acc = {0.f, 0.f, 0.f, 0.f};

  for (int br = 0; br < 2; ++br) {
    size_t rbase = ((size_t)br * NROW + row) * MAXNNZ;
    int n = cnt[br * NROW + row];
    const float* srcv = sdv + (2 * br) * NROW;
    const float* dstv = sdv + (2 * br + 1) * NROW;
    float e = -1e30f;
    if (t < n) {
      int j = idx[rbase + t];
      sj[t] = j;
      float v = srcv[row] + dstv[j];
      e = v >= 0.f ? v : 0.01f * v;
    }
    float m = e;
    for (int o = 32; o; o >>= 1) m = fmaxf(m, __shfl_xor(m, o));
    if ((t & 63) == 0) red[t >> 6] = m;
    __syncthreads();
    m = fmaxf(fmaxf(red[0], red[1]), fmaxf(red[2], red[3]));
    __syncthreads();
    float p = (t < n) ? expf(e - m) : 0.f;
    float s = p;
    for (int o = 32; o; o >>= 1) s += __shfl_xor(s, o);
    if ((t & 63) == 0) red[t >> 6] = s;
    __syncthreads();
    s = red[0] + red[1] + red[2] + red[3];
    if (t < n) sa[t] = p / s;
    __syncthreads();
    int cd = br ? 512 : 0;
    for (int k = w; k < n; k += 4) {
      ushort4 y = *(const ushort4*)(Y + (size_t)sj[k] * 1280 + cd + 4 * l);
      float a = sa[k];
      acc.x += a * bf2f(y.x); acc.y += a * bf2f(y.y);
      acc.z += a * bf2f(y.z); acc.w += a * bf2f(y.w);
    }
    __syncthreads();
  }

  {
    size_t rbase = ((size_t)2 * NROW + row) * MAXNNZ;
    int n = cnt[2 * NROW + row];
    if (t < n) { sj[t] = idx[rbase + t]; sa[t] = val[rbase + t]; }
    __syncthreads();
    for (int k = w; k < n; k += 4) {
      ushort4 y = *(const ushort4*)(Y + (size_t)sj[k] * 1280 + 1024 + 4 * l);
      float a = sa[k];
      acc.x += a * bf2f(y.x); acc.y += a * bf2f(y.y);
      acc.z += a * bf2f(y.z); acc.w += a * bf2f(y.w);
    }
  }
  ((float4*)part[w])[l] = acc;
  __syncthreads();
  if (t < 64) {
    float4 r;
    int c = 4 * t;
    r.x = part[0][c]     + part[1][c]     + part[2][c]     + part[3][c]     + bi[c]     + bi[256 + c] + bs[c]     + bs[256 + c] + bh[c];
    r.y = part[0][c + 1] + part[1][c + 1] + part[2][c + 1] + part[3][c + 1] + bi[c + 1] + bi[257 + c] + bs[c + 1] + bs[257 + c] + bh[c + 1];
    r.z = part[0][c + 2] + part[1][c + 2] + part[2][c + 2] + part[3][c + 2] + bi[c + 2] + bi[258 + c] + bs[c + 2] + bs[258 + c] + bh[c + 2];
    r.w = part[0][c + 3] + part[1][c + 3] + part[2][c + 3] + part[3][c + 3] + bi[c + 3] + bi[259 + c] + bs[c + 3] + bs[259 + c] + bh[c + 3];
    *(float4*)(Z + (size_t)row * 256 + c) = r;
  }
}

// ---------------------------------------------------------------------------
extern "C" void kernel_launch(void* const* d_in, const int* in_sizes, int n_in,
                              void* d_out, int out_size, void* d_ws, size_t ws_size,
                              hipStream_t stream) {
  const float* x      = (const float*)d_in[0];
  const float* Lup    = (const float*)d_in[1];
  const float* Ld     = (const float*)d_in[2];
  const float* P      = (const float*)d_in[3];
  const float* Wirr_w = (const float*)d_in[4];
  const float* Wirr_b = (const float*)d_in[5];
  const float* Wsol_w = (const float*)d_in[6];
  const float* Wsol_b = (const float*)d_in[7];
  const float* Whar_w = (const float*)d_in[8];
  const float* Whar_b = (const float*)d_in[9];
  const float* att_i  = (const float*)d_in[10];
  const float* att_s  = (const float*)d_in[11];
  float* Z = (float*)d_out;

  char* w = (char*)d_ws;
  auto alloc = [&](size_t bytes) { void* p = (void*)w; w += (bytes + 255) & ~(size_t)255; return p; };

  int*   idx  = (int*)alloc((size_t)3 * NROW * MAXNNZ * 4);
  float* val  = (float*)alloc((size_t)3 * NROW * MAXNNZ * 4);
  int*   cnt  = (int*)alloc((size_t)3 * NROW * 4);
  float* sdv  = (float*)alloc(4 * NROW * 4);
  unsigned short* xbf = (unsigned short*)alloc((size_t)NROW * CH * 2);
  unsigned short* Bbf = (unsigned short*)alloc((size_t)1280 * CH * 2);
  unsigned short* Y   = (unsigned short*)alloc((size_t)NROW * 1280 * 2);

  cvt_all<<<(262144 + 32768 + 32768 + 16384) / 256, 256, 0, stream>>>(x, Wirr_w, Wsol_w, Whar_w, xbf, Bbf);

  // mat slot order: 0 = Ld (irr), 1 = Lup (sol), 2 = P
  scan_gemm<<<13568, 256, 0, stream>>>(Ld, Lup, P, idx, val, cnt, xbf, Bbf, Y);

  spmm_sdv<<<NROW, 256, 0, stream>>>(idx, val, cnt, att_i, att_s, Wirr_b, Wsol_b, Y, sdv);

  final_z<<<NROW, 256, 0, stream>>>(idx, val, cnt, sdv, Y, Wirr_b, Wsol_b, Whar_b, Z);
}